// Round 4
// baseline (864.906 us; speedup 1.0000x reference)
//
#include <hip/hip_runtime.h>
#include <hip/hip_fp16.h>

// PillarFeatureNet: out = scatter_add(relu(BN(x@W^T + b)), cells), grid 512x512x64.
// BN stats from x's 6x6 covariance (bias cancels in var); BN+ReLU folded into the
// linear. Deterministic two-level counting sort carrying FAT records (x packed as
// 3x half2 + cell_local, 16B) so the accumulate pass is 100% sequential — no
// random gathers, no global atomics, no memsets.

constexpr int NPTS   = 2000000;
constexpr int NBUCK  = 2048;   // coarse buckets = cell >> 7
constexpr int CPB    = 128;    // cells per bucket
constexpr int NBLK   = 256;    // partition blocks for hist/scatter
constexpr int CHUNK  = 7813;   // ceil(NPTS / NBLK)
constexpr float EPS  = 1e-5f;

// Workspace layout (4-byte elements):
constexpr int WS_WPH    = 0;                          // 64*3 packed half2 folded weights
constexpr int WS_BP     = 192;                        // 64 folded bias (f32)
constexpr int WS_STARTS = 256;                        // NBUCK+1 bucket starts
constexpr int WS_HIST   = 2560;                       // NBLK*NBUCK per-block hist
constexpr int WS_BASES  = WS_HIST + NBLK * NBUCK;     // NBLK*NBUCK per-(block,bucket) bases
constexpr int WS_BSTATS = WS_BASES + NBLK * NBUCK;    // NBLK*32 partial stats
constexpr int WS_SORTED = WS_BSTATS + NBLK * 32;      // NPTS uint4 records (16B-aligned)
// total = 1,059,328 + 8,000,000 elems ≈ 36.3 MB

typedef _Float16 h2v __attribute__((ext_vector_type(2)));

__device__ __forceinline__ float dot2u(unsigned int a, unsigned int b, float c) {
#if __has_builtin(__builtin_amdgcn_fdot2)
    union { unsigned int u; h2v h; } ca, cb;
    ca.u = a; cb.u = b;
    return __builtin_amdgcn_fdot2(ca.h, cb.h, c, false);
#else
    union { unsigned int u; __half2 h; } ca, cb;
    ca.u = a; cb.u = b;
    float2 fa = __half22float2(ca.h), fb = __half22float2(cb.h);
    return fmaf(fa.x, fb.x, fmaf(fa.y, fb.y, c));
#endif
}

__device__ __forceinline__ float wave_sum64(float v) {
#pragma unroll
    for (int off = 32; off > 0; off >>= 1) v += __shfl_down(v, off, 64);
    return v;
}

// ---- K1: per-block histogram over 2048 buckets (no global atomics) ----
__global__ __launch_bounds__(1024) void hist_kernel(const int2* __restrict__ idx,
                                                    int* __restrict__ hist) {
    __shared__ int lh[NBUCK];
    for (int i = threadIdx.x; i < NBUCK; i += 1024) lh[i] = 0;
    __syncthreads();
    const int beg = blockIdx.x * CHUNK;
    const int end = min(NPTS, beg + CHUNK);
    for (int p = beg + threadIdx.x; p < end; p += 1024) {
        const int2 ij = idx[p];
        atomicAdd(&lh[(ij.x << 2) | (ij.y >> 7)], 1);
    }
    __syncthreads();
    int* out = hist + blockIdx.x * NBUCK;
    for (int i = threadIdx.x; i < NBUCK; i += 1024) out[i] = lh[i];
}

// ---- K2a: column scan over blocks -> per-(block,bucket) bases + bucket totals ----
__global__ __launch_bounds__(64) void colscan_kernel(const int* __restrict__ hist,
                                                     int* __restrict__ bases,
                                                     int* __restrict__ starts) {
    const int b = blockIdx.x * 64 + threadIdx.x;
    int run = 0;
    for (int blk = 0; blk < NBLK; ++blk) {
        bases[blk * NBUCK + b] = run;
        run += hist[blk * NBUCK + b];
    }
    starts[b] = run;
}

// ---- K2b: exclusive scan of 2048 bucket totals (in place) ----
__global__ __launch_bounds__(1024) void scan_kernel(int* __restrict__ starts) {
    __shared__ int wsum[16];
    const int t = threadIdx.x, lane = t & 63, wv = t >> 6;
    const int v0 = starts[2 * t], v1 = starts[2 * t + 1];
    const int v = v0 + v1;
    int incl = v;
#pragma unroll
    for (int d = 1; d < 64; d <<= 1) {
        int u = __shfl_up(incl, d, 64);
        if (lane >= d) incl += u;
    }
    if (lane == 63) wsum[wv] = incl;
    __syncthreads();
    int pre = 0;
#pragma unroll
    for (int w = 0; w < 16; ++w) {
        int sv = wsum[w];
        if (w < wv) pre += sv;
    }
    const int excl = pre + incl - v;
    starts[2 * t] = excl;
    starts[2 * t + 1] = excl + v0;
    if (t == 1023) starts[NBUCK] = excl + v;  // == NPTS
}

// ---- K3: scatter fat records to exact final slots + x stats (no global atomics) ----
__global__ __launch_bounds__(1024) void scatter_kernel(const float* __restrict__ x,
                                                       const int2* __restrict__ idx,
                                                       const int* __restrict__ starts,
                                                       const int* __restrict__ bases,
                                                       uint4* __restrict__ sorted4,
                                                       float* __restrict__ bstats) {
    __shared__ int lbase[NBUCK];
    __shared__ int lcur[NBUCK];
    __shared__ float lstats[16][27];
    const int blk = blockIdx.x;
    for (int i = threadIdx.x; i < NBUCK; i += 1024) {
        lbase[i] = starts[i] + bases[blk * NBUCK + i];
        lcur[i] = 0;
    }
    __syncthreads();

    float acc[27];
#pragma unroll
    for (int i = 0; i < 27; ++i) acc[i] = 0.f;

    const int beg = blk * CHUNK;
    const int end = min(NPTS, beg + CHUNK);
    for (int p = beg + threadIdx.x; p < end; p += 1024) {
        const int2 ij = idx[p];
        const float2* xp = (const float2*)(x + (size_t)p * 6);
        const float2 a = xp[0], bq = xp[1], cq = xp[2];
        float v[6] = {a.x, a.y, bq.x, bq.y, cq.x, cq.y};
        int c = 6;
#pragma unroll
        for (int k = 0; k < 6; ++k) {
            acc[k] += v[k];
#pragma unroll
            for (int l = k; l < 6; ++l) { acc[c] += v[k] * v[l]; ++c; }
        }
        __half2 h0 = __floats2half2_rn(a.x, a.y);
        __half2 h1 = __floats2half2_rn(bq.x, bq.y);
        __half2 h2 = __floats2half2_rn(cq.x, cq.y);
        const int b = (ij.x << 2) | (ij.y >> 7);
        const int rank = atomicAdd(&lcur[b], 1);  // LDS returning atomic
        uint4 r;
        r.x = *(const unsigned int*)&h0;
        r.y = *(const unsigned int*)&h1;
        r.z = *(const unsigned int*)&h2;
        r.w = (unsigned int)(ij.y & 127);
        sorted4[lbase[b] + rank] = r;
    }

    const int lane = threadIdx.x & 63, wv = threadIdx.x >> 6;
#pragma unroll
    for (int i = 0; i < 27; ++i) {
        const float s = wave_sum64(acc[i]);
        if (lane == 0) lstats[wv][i] = s;
    }
    __syncthreads();
    if (threadIdx.x < 27) {
        float s = 0.f;
        for (int w = 0; w < 16; ++w) s += lstats[w][threadIdx.x];
        bstats[blk * 32 + threadIdx.x] = s;
    }
}

// ---- K3b: reduce stats, fold BN into linear, pack half2 weights ----
__global__ __launch_bounds__(64) void bnfold_kernel(const float* __restrict__ bstats,
                                                    const float* __restrict__ W,
                                                    const float* __restrict__ b,
                                                    const float* __restrict__ gamma,
                                                    const float* __restrict__ beta,
                                                    float* __restrict__ ws) {
    __shared__ float s27[27];
    __shared__ float m[6], C[36];
    const int t = threadIdx.x;
    if (t < 27) {
        float s = 0.f;
        for (int blk = 0; blk < NBLK; ++blk) s += bstats[blk * 32 + t];
        s27[t] = s;
    }
    __syncthreads();
    if (t == 0) {
        const float invN = 1.0f / (float)NPTS;
        float mm[6];
        for (int k = 0; k < 6; ++k) { mm[k] = s27[k] * invN; m[k] = mm[k]; }
        int c = 6;
        for (int k = 0; k < 6; ++k)
            for (int l = k; l < 6; ++l) {
                const float cov = s27[c] * invN - mm[k] * mm[l];
                ++c;
                C[k * 6 + l] = cov;
                C[l * 6 + k] = cov;
            }
    }
    __syncthreads();
    float w[6];
#pragma unroll
    for (int k = 0; k < 6; ++k) w[k] = W[t * 6 + k];
    float mh = b[t];
#pragma unroll
    for (int k = 0; k < 6; ++k) mh += w[k] * m[k];
    float var = 0.f;
#pragma unroll
    for (int k = 0; k < 6; ++k)
#pragma unroll
        for (int l = 0; l < 6; ++l) var += w[k] * w[l] * C[k * 6 + l];
    const float s = gamma[t] * rsqrtf(var + EPS);
    float wp[6];
#pragma unroll
    for (int k = 0; k < 6; ++k) wp[k] = w[k] * s;
    unsigned int* wsu = (unsigned int*)ws;
    __half2 p0 = __floats2half2_rn(wp[0], wp[1]);
    __half2 p1 = __floats2half2_rn(wp[2], wp[3]);
    __half2 p2 = __floats2half2_rn(wp[4], wp[5]);
    wsu[WS_WPH + t * 3 + 0] = *(const unsigned int*)&p0;
    wsu[WS_WPH + t * 3 + 1] = *(const unsigned int*)&p1;
    wsu[WS_WPH + t * 3 + 2] = *(const unsigned int*)&p2;
    ws[WS_BP + t] = beta[t] + s * (b[t] - mh);
}

// ---- K4: one block per bucket; sequential record stream -> LDS slab -> store ----
__global__ __launch_bounds__(1024) void accum_kernel(const uint4* __restrict__ sorted4,
                                                     const int* __restrict__ starts,
                                                     const float* __restrict__ wsf,
                                                     float* __restrict__ grid) {
    __shared__ float slab[CPB * 64];   // 32 KB
    __shared__ uint4 stage[1024];      // 16 KB
    const int t = threadIdx.x, lane = t & 63, wv = t >> 6;

    float4* s4 = (float4*)slab;
    for (int i = t; i < CPB * 16; i += 1024) s4[i] = make_float4(0.f, 0.f, 0.f, 0.f);

    const unsigned int* wsu = (const unsigned int*)wsf;
    const unsigned int wp0 = wsu[WS_WPH + lane * 3 + 0];
    const unsigned int wp1 = wsu[WS_WPH + lane * 3 + 1];
    const unsigned int wp2 = wsu[WS_WPH + lane * 3 + 2];
    const float bb = wsf[WS_BP + lane];

    const int s = starts[blockIdx.x];
    const int e = starts[blockIdx.x + 1];

    for (int base = s; base < e; base += 1024) {
        __syncthreads();  // slab zero / previous chunk's adds complete
        const int n = min(1024, e - base);
        if (t < n) stage[t] = sorted4[base + t];  // coalesced 16 KB
        __syncthreads();
        const int lo = wv * 64, hi = min(lo + 64, n);
        float acc = 0.f;
        int cur = -1;
        for (int p = lo; p < hi; ++p) {
            const uint4 r = stage[p];             // broadcast ds_read_b128
            const int cell = (int)r.w;
            if (cell != cur) {                    // wave-uniform branch
                if (cur >= 0) atomicAdd(&slab[cur * 64 + lane], acc);
                acc = 0.f;
                cur = cell;
            }
            const float h = dot2u(r.x, wp0, dot2u(r.y, wp1, dot2u(r.z, wp2, bb)));
            acc += fmaxf(h, 0.f);
        }
        if (cur >= 0) atomicAdd(&slab[cur * 64 + lane], acc);
    }
    __syncthreads();

    float4* g4 = (float4*)(grid + (size_t)blockIdx.x * CPB * 64);
    for (int i = t; i < CPB * 16; i += 1024) g4[i] = s4[i];
}

extern "C" void kernel_launch(void* const* d_in, const int* in_sizes, int n_in,
                              void* d_out, int out_size, void* d_ws, size_t ws_size,
                              hipStream_t stream) {
    const float* x       = (const float*)d_in[0];
    const int2*  indices = (const int2*)d_in[1];
    const float* W       = (const float*)d_in[2];
    const float* b       = (const float*)d_in[3];
    const float* gamma   = (const float*)d_in[4];
    const float* beta    = (const float*)d_in[5];
    float* out = (float*)d_out;
    float* wsf = (float*)d_ws;
    int*   wsi = (int*)d_ws;

    int*   hist    = wsi + WS_HIST;
    int*   bases   = wsi + WS_BASES;
    int*   starts  = wsi + WS_STARTS;
    uint4* sorted4 = (uint4*)(wsi + WS_SORTED);
    float* bstats  = wsf + WS_BSTATS;

    hist_kernel<<<NBLK, 1024, 0, stream>>>(indices, hist);
    colscan_kernel<<<NBUCK / 64, 64, 0, stream>>>(hist, bases, starts);
    scan_kernel<<<1, 1024, 0, stream>>>(starts);
    scatter_kernel<<<NBLK, 1024, 0, stream>>>(x, indices, starts, bases, sorted4, bstats);
    bnfold_kernel<<<1, 64, 0, stream>>>(bstats, W, b, gamma, beta, wsf);
    accum_kernel<<<NBUCK, 1024, 0, stream>>>(sorted4, starts, wsf, out);
}

// Round 5
// 834.858 us; speedup vs baseline: 1.0360x; 1.0360x over previous
//
#include <hip/hip_runtime.h>
#include <hip/hip_fp16.h>

// PillarFeatureNet: out = scatter_add(relu(BN(x@W^T + b)), cells), grid 512x512x64.
// BN stats from x's 6x6 covariance (bias cancels in var); BN+ReLU folded into the
// linear. Deterministic two-level counting sort carrying fat records (x as 3x half2
// + cell_local, 16B). Accum pass: one coalesced record load per wave-window, then
// branchless unrolled readlane-broadcast loop -> conflict-free ds_add into LDS slab.

constexpr int NPTS   = 2000000;
constexpr int NBUCK  = 2048;   // coarse buckets = cell >> 7
constexpr int CPB    = 128;    // cells per bucket
constexpr int NBLK   = 256;    // partition blocks for hist/scatter
constexpr int CHUNK  = 7813;   // ceil(NPTS / NBLK)
constexpr float EPS  = 1e-5f;

// Workspace layout (4-byte elements):
constexpr int WS_WPH    = 0;                          // 64*3 packed half2 folded weights
constexpr int WS_BP     = 192;                        // 64 folded bias (f32)
constexpr int WS_STARTS = 256;                        // NBUCK+1 bucket starts
constexpr int WS_HIST   = 2560;                       // NBLK*NBUCK per-block hist
constexpr int WS_BASES  = WS_HIST + NBLK * NBUCK;     // NBLK*NBUCK per-(block,bucket) bases
constexpr int WS_BSTATS = WS_BASES + NBLK * NBUCK;    // NBLK*32 partial stats
constexpr int WS_SORTED = WS_BSTATS + NBLK * 32;      // NPTS uint4 records (16B-aligned)

typedef _Float16 h2v __attribute__((ext_vector_type(2)));

__device__ __forceinline__ float dot2u(unsigned int a, unsigned int b, float c) {
    union { unsigned int u; h2v h; } ca, cb;
    ca.u = a; cb.u = b;
    return __builtin_amdgcn_fdot2(ca.h, cb.h, c, false);
}

__device__ __forceinline__ float wave_sum64(float v) {
#pragma unroll
    for (int off = 32; off > 0; off >>= 1) v += __shfl_down(v, off, 64);
    return v;
}

// ---- K1: per-block histogram over 2048 buckets (no global atomics) ----
__global__ __launch_bounds__(1024) void hist_kernel(const int2* __restrict__ idx,
                                                    int* __restrict__ hist) {
    __shared__ int lh[NBUCK];
    for (int i = threadIdx.x; i < NBUCK; i += 1024) lh[i] = 0;
    __syncthreads();
    const int beg = blockIdx.x * CHUNK;
    const int end = min(NPTS, beg + CHUNK);
    for (int p = beg + threadIdx.x; p < end; p += 1024) {
        const int2 ij = idx[p];
        atomicAdd(&lh[(ij.x << 2) | (ij.y >> 7)], 1);
    }
    __syncthreads();
    int* out = hist + blockIdx.x * NBUCK;
    for (int i = threadIdx.x; i < NBUCK; i += 1024) out[i] = lh[i];
}

// ---- K2a: column scan over blocks -> per-(block,bucket) bases + bucket totals ----
__global__ __launch_bounds__(64) void colscan_kernel(const int* __restrict__ hist,
                                                     int* __restrict__ bases,
                                                     int* __restrict__ starts) {
    const int b = blockIdx.x * 64 + threadIdx.x;
    int run = 0;
    for (int blk = 0; blk < NBLK; ++blk) {
        bases[blk * NBUCK + b] = run;
        run += hist[blk * NBUCK + b];
    }
    starts[b] = run;
}

// ---- K2b: exclusive scan of 2048 bucket totals (in place) ----
__global__ __launch_bounds__(1024) void scan_kernel(int* __restrict__ starts) {
    __shared__ int wsum[16];
    const int t = threadIdx.x, lane = t & 63, wv = t >> 6;
    const int v0 = starts[2 * t], v1 = starts[2 * t + 1];
    const int v = v0 + v1;
    int incl = v;
#pragma unroll
    for (int d = 1; d < 64; d <<= 1) {
        int u = __shfl_up(incl, d, 64);
        if (lane >= d) incl += u;
    }
    if (lane == 63) wsum[wv] = incl;
    __syncthreads();
    int pre = 0;
#pragma unroll
    for (int w = 0; w < 16; ++w) {
        int sv = wsum[w];
        if (w < wv) pre += sv;
    }
    const int excl = pre + incl - v;
    starts[2 * t] = excl;
    starts[2 * t + 1] = excl + v0;
    if (t == 1023) starts[NBUCK] = excl + v;  // == NPTS
}

// ---- K3: scatter fat records to exact final slots + x stats (no global atomics) ----
__global__ __launch_bounds__(1024) void scatter_kernel(const float* __restrict__ x,
                                                       const int2* __restrict__ idx,
                                                       const int* __restrict__ starts,
                                                       const int* __restrict__ bases,
                                                       uint4* __restrict__ sorted4,
                                                       float* __restrict__ bstats) {
    __shared__ int lbase[NBUCK];
    __shared__ int lcur[NBUCK];
    __shared__ float lstats[16][27];
    const int blk = blockIdx.x;
    for (int i = threadIdx.x; i < NBUCK; i += 1024) {
        lbase[i] = starts[i] + bases[blk * NBUCK + i];
        lcur[i] = 0;
    }
    __syncthreads();

    float acc[27];
#pragma unroll
    for (int i = 0; i < 27; ++i) acc[i] = 0.f;

    const int beg = blk * CHUNK;
    const int end = min(NPTS, beg + CHUNK);
    for (int p = beg + threadIdx.x; p < end; p += 1024) {
        const int2 ij = idx[p];
        const float2* xp = (const float2*)(x + (size_t)p * 6);
        const float2 a = xp[0], bq = xp[1], cq = xp[2];
        float v[6] = {a.x, a.y, bq.x, bq.y, cq.x, cq.y};
        int c = 6;
#pragma unroll
        for (int k = 0; k < 6; ++k) {
            acc[k] += v[k];
#pragma unroll
            for (int l = k; l < 6; ++l) { acc[c] += v[k] * v[l]; ++c; }
        }
        __half2 h0 = __floats2half2_rn(a.x, a.y);
        __half2 h1 = __floats2half2_rn(bq.x, bq.y);
        __half2 h2 = __floats2half2_rn(cq.x, cq.y);
        const int b = (ij.x << 2) | (ij.y >> 7);
        const int rank = atomicAdd(&lcur[b], 1);  // LDS returning atomic
        uint4 r;
        r.x = *(const unsigned int*)&h0;
        r.y = *(const unsigned int*)&h1;
        r.z = *(const unsigned int*)&h2;
        r.w = (unsigned int)(ij.y & 127);
        sorted4[lbase[b] + rank] = r;
    }

    const int lane = threadIdx.x & 63, wv = threadIdx.x >> 6;
#pragma unroll
    for (int i = 0; i < 27; ++i) {
        const float s = wave_sum64(acc[i]);
        if (lane == 0) lstats[wv][i] = s;
    }
    __syncthreads();
    if (threadIdx.x < 27) {
        float s = 0.f;
        for (int w = 0; w < 16; ++w) s += lstats[w][threadIdx.x];
        bstats[blk * 32 + threadIdx.x] = s;
    }
}

// ---- K3b: reduce stats, fold BN into linear, pack half2 weights ----
__global__ __launch_bounds__(64) void bnfold_kernel(const float* __restrict__ bstats,
                                                    const float* __restrict__ W,
                                                    const float* __restrict__ b,
                                                    const float* __restrict__ gamma,
                                                    const float* __restrict__ beta,
                                                    float* __restrict__ ws) {
    __shared__ float s27[27];
    __shared__ float m[6], C[36];
    const int t = threadIdx.x;
    if (t < 27) {
        float s = 0.f;
        for (int blk = 0; blk < NBLK; ++blk) s += bstats[blk * 32 + t];
        s27[t] = s;
    }
    __syncthreads();
    if (t == 0) {
        const float invN = 1.0f / (float)NPTS;
        float mm[6];
        for (int k = 0; k < 6; ++k) { mm[k] = s27[k] * invN; m[k] = mm[k]; }
        int c = 6;
        for (int k = 0; k < 6; ++k)
            for (int l = k; l < 6; ++l) {
                const float cov = s27[c] * invN - mm[k] * mm[l];
                ++c;
                C[k * 6 + l] = cov;
                C[l * 6 + k] = cov;
            }
    }
    __syncthreads();
    float w[6];
#pragma unroll
    for (int k = 0; k < 6; ++k) w[k] = W[t * 6 + k];
    float mh = b[t];
#pragma unroll
    for (int k = 0; k < 6; ++k) mh += w[k] * m[k];
    float var = 0.f;
#pragma unroll
    for (int k = 0; k < 6; ++k)
#pragma unroll
        for (int l = 0; l < 6; ++l) var += w[k] * w[l] * C[k * 6 + l];
    const float s = gamma[t] * rsqrtf(var + EPS);
    float wp[6];
#pragma unroll
    for (int k = 0; k < 6; ++k) wp[k] = w[k] * s;
    unsigned int* wsu = (unsigned int*)ws;
    __half2 p0 = __floats2half2_rn(wp[0], wp[1]);
    __half2 p1 = __floats2half2_rn(wp[2], wp[3]);
    __half2 p2 = __floats2half2_rn(wp[4], wp[5]);
    wsu[WS_WPH + t * 3 + 0] = *(const unsigned int*)&p0;
    wsu[WS_WPH + t * 3 + 1] = *(const unsigned int*)&p1;
    wsu[WS_WPH + t * 3 + 2] = *(const unsigned int*)&p2;
    ws[WS_BP + t] = beta[t] + s * (b[t] - mh);
}

// ---- K4: one block per bucket; coalesced register windows; branchless readlane
//          broadcast loop; ds_add_f32 slab; single coalesced store ----
__global__ __launch_bounds__(256) void accum_kernel(const uint4* __restrict__ sorted4,
                                                    const int* __restrict__ starts,
                                                    const float* __restrict__ wsf,
                                                    float* __restrict__ grid) {
    __shared__ float slab[CPB * 64];   // 32 KB
    const int t = threadIdx.x, lane = t & 63, wv = t >> 6;

    float4* s4 = (float4*)slab;
    for (int i = t; i < CPB * 16; i += 256) s4[i] = make_float4(0.f, 0.f, 0.f, 0.f);

    const unsigned int* wsu = (const unsigned int*)wsf;
    const unsigned int wp0 = wsu[WS_WPH + lane * 3 + 0];
    const unsigned int wp1 = wsu[WS_WPH + lane * 3 + 1];
    const unsigned int wp2 = wsu[WS_WPH + lane * 3 + 2];
    const float bb = wsf[WS_BP + lane];

    const int s = starts[blockIdx.x];
    const int e = starts[blockIdx.x + 1];
    __syncthreads();

    // 4 waves stride 64-record windows across the bucket. Lane l holds record
    // base+l in registers (one coalesced 16B/lane load). Then a straight-line
    // unrolled loop broadcasts each record via v_readlane and every lane (=feature)
    // does one conflict-free ds_add_f32. No data-dependent branches, no per-record
    // memory latency in the loop.
    for (int base = s + wv * 64; base < e; base += 4 * 64) {
        const int n = min(64, e - base);
        uint4 rec = make_uint4(0u, 0u, 0u, 0u);
        if (lane < n) rec = sorted4[base + lane];

#define PT_BODY(PT)                                                                  \
        {                                                                            \
            const unsigned int c  = __builtin_amdgcn_readlane(rec.w, (PT));          \
            const unsigned int x0 = __builtin_amdgcn_readlane(rec.x, (PT));          \
            const unsigned int x1 = __builtin_amdgcn_readlane(rec.y, (PT));          \
            const unsigned int x2 = __builtin_amdgcn_readlane(rec.z, (PT));          \
            const float h = dot2u(x0, wp0, dot2u(x1, wp1, dot2u(x2, wp2, bb)));      \
            atomicAdd(&slab[c * 64 + lane], fmaxf(h, 0.f));                          \
        }
        if (n == 64) {
#pragma unroll
            for (int pt = 0; pt < 64; ++pt) PT_BODY(pt)
        } else {
            for (int pt = 0; pt < n; ++pt) PT_BODY(pt)
        }
#undef PT_BODY
    }
    __syncthreads();

    float4* g4 = (float4*)(grid + (size_t)blockIdx.x * CPB * 64);
    for (int i = t; i < CPB * 16; i += 256) g4[i] = s4[i];
}

extern "C" void kernel_launch(void* const* d_in, const int* in_sizes, int n_in,
                              void* d_out, int out_size, void* d_ws, size_t ws_size,
                              hipStream_t stream) {
    const float* x       = (const float*)d_in[0];
    const int2*  indices = (const int2*)d_in[1];
    const float* W       = (const float*)d_in[2];
    const float* b       = (const float*)d_in[3];
    const float* gamma   = (const float*)d_in[4];
    const float* beta    = (const float*)d_in[5];
    float* out = (float*)d_out;
    float* wsf = (float*)d_ws;
    int*   wsi = (int*)d_ws;

    int*   hist    = wsi + WS_HIST;
    int*   bases   = wsi + WS_BASES;
    int*   starts  = wsi + WS_STARTS;
    uint4* sorted4 = (uint4*)(wsi + WS_SORTED);
    float* bstats  = wsf + WS_BSTATS;

    hist_kernel<<<NBLK, 1024, 0, stream>>>(indices, hist);
    colscan_kernel<<<NBUCK / 64, 64, 0, stream>>>(hist, bases, starts);
    scan_kernel<<<1, 1024, 0, stream>>>(starts);
    scatter_kernel<<<NBLK, 1024, 0, stream>>>(x, indices, starts, bases, sorted4, bstats);
    bnfold_kernel<<<1, 64, 0, stream>>>(bstats, W, b, gamma, beta, wsf);
    accum_kernel<<<NBUCK, 256, 0, stream>>>(sorted4, starts, wsf, out);
}

// Round 6
// 252.549 us; speedup vs baseline: 3.4247x; 3.3057x over previous
//
#include <hip/hip_runtime.h>
#include <hip/hip_fp16.h>

// PillarFeatureNet: out = scatter_add(relu(BN(x@W^T + b)), cells), grid 512x512x64.
// BN stats from x's 6x6 covariance (bias cancels in var); BN+ReLU folded into the
// linear. Two-level deterministic sort carrying fat records (x as 3x half2 +
// cell_local, 16B). Accum: within-bucket cell sort in LDS (int atomics only),
// then per-cell REGISTER accumulation — zero LDS float atomics (measured ~200
// cyc/op on gfx950 across R3/R4/R5), zero global atomics, single coalesced store.

constexpr int NPTS   = 2000000;
constexpr int NBUCK  = 2048;   // coarse buckets = cell >> 7
constexpr int CPB    = 128;    // cells per bucket
constexpr int NBLK   = 256;    // partition blocks for hist/scatter
constexpr int CHUNK  = 7813;   // ceil(NPTS / NBLK)
constexpr float EPS  = 1e-5f;

// Workspace layout (4-byte elements):
constexpr int WS_WPH    = 0;                          // 64*3 packed half2 folded weights
constexpr int WS_BP     = 192;                        // 64 folded bias (f32)
constexpr int WS_STARTS = 256;                        // NBUCK+1 bucket starts
constexpr int WS_HIST   = 2560;                       // NBLK*NBUCK per-block hist
constexpr int WS_BASES  = WS_HIST + NBLK * NBUCK;     // NBLK*NBUCK per-(block,bucket) bases
constexpr int WS_BSTATS = WS_BASES + NBLK * NBUCK;    // NBLK*32 partial stats
constexpr int WS_SORTED = WS_BSTATS + NBLK * 32;      // NPTS uint4 records (16B-aligned)

typedef _Float16 h2v __attribute__((ext_vector_type(2)));

__device__ __forceinline__ float dot2u(unsigned int a, unsigned int b, float c) {
    union { unsigned int u; h2v h; } ca, cb;
    ca.u = a; cb.u = b;
    return __builtin_amdgcn_fdot2(ca.h, cb.h, c, false);
}

__device__ __forceinline__ float wave_sum64(float v) {
#pragma unroll
    for (int off = 32; off > 0; off >>= 1) v += __shfl_down(v, off, 64);
    return v;
}

// ---- K1: per-block histogram over 2048 buckets (no global atomics) ----
__global__ __launch_bounds__(1024) void hist_kernel(const int2* __restrict__ idx,
                                                    int* __restrict__ hist) {
    __shared__ int lh[NBUCK];
    for (int i = threadIdx.x; i < NBUCK; i += 1024) lh[i] = 0;
    __syncthreads();
    const int beg = blockIdx.x * CHUNK;
    const int end = min(NPTS, beg + CHUNK);
    for (int p = beg + threadIdx.x; p < end; p += 1024) {
        const int2 ij = idx[p];
        atomicAdd(&lh[(ij.x << 2) | (ij.y >> 7)], 1);
    }
    __syncthreads();
    int* out = hist + blockIdx.x * NBUCK;
    for (int i = threadIdx.x; i < NBUCK; i += 1024) out[i] = lh[i];
}

// ---- K2a: column scan over blocks -> per-(block,bucket) bases + bucket totals ----
__global__ __launch_bounds__(64) void colscan_kernel(const int* __restrict__ hist,
                                                     int* __restrict__ bases,
                                                     int* __restrict__ starts) {
    const int b = blockIdx.x * 64 + threadIdx.x;
    int run = 0;
    for (int blk = 0; blk < NBLK; ++blk) {
        bases[blk * NBUCK + b] = run;
        run += hist[blk * NBUCK + b];
    }
    starts[b] = run;
}

// ---- K2b: exclusive scan of 2048 bucket totals (in place) ----
__global__ __launch_bounds__(1024) void scan_kernel(int* __restrict__ starts) {
    __shared__ int wsum[16];
    const int t = threadIdx.x, lane = t & 63, wv = t >> 6;
    const int v0 = starts[2 * t], v1 = starts[2 * t + 1];
    const int v = v0 + v1;
    int incl = v;
#pragma unroll
    for (int d = 1; d < 64; d <<= 1) {
        int u = __shfl_up(incl, d, 64);
        if (lane >= d) incl += u;
    }
    if (lane == 63) wsum[wv] = incl;
    __syncthreads();
    int pre = 0;
#pragma unroll
    for (int w = 0; w < 16; ++w) {
        int sv = wsum[w];
        if (w < wv) pre += sv;
    }
    const int excl = pre + incl - v;
    starts[2 * t] = excl;
    starts[2 * t + 1] = excl + v0;
    if (t == 1023) starts[NBUCK] = excl + v;  // == NPTS
}

// ---- K3: scatter fat records to exact final slots + x stats (no global atomics) ----
__global__ __launch_bounds__(1024) void scatter_kernel(const float* __restrict__ x,
                                                       const int2* __restrict__ idx,
                                                       const int* __restrict__ starts,
                                                       const int* __restrict__ bases,
                                                       uint4* __restrict__ sorted4,
                                                       float* __restrict__ bstats) {
    __shared__ int lbase[NBUCK];
    __shared__ int lcur[NBUCK];
    __shared__ float lstats[16][27];
    const int blk = blockIdx.x;
    for (int i = threadIdx.x; i < NBUCK; i += 1024) {
        lbase[i] = starts[i] + bases[blk * NBUCK + i];
        lcur[i] = 0;
    }
    __syncthreads();

    float acc[27];
#pragma unroll
    for (int i = 0; i < 27; ++i) acc[i] = 0.f;

    const int beg = blk * CHUNK;
    const int end = min(NPTS, beg + CHUNK);
    for (int p = beg + threadIdx.x; p < end; p += 1024) {
        const int2 ij = idx[p];
        const float2* xp = (const float2*)(x + (size_t)p * 6);
        const float2 a = xp[0], bq = xp[1], cq = xp[2];
        float v[6] = {a.x, a.y, bq.x, bq.y, cq.x, cq.y};
        int c = 6;
#pragma unroll
        for (int k = 0; k < 6; ++k) {
            acc[k] += v[k];
#pragma unroll
            for (int l = k; l < 6; ++l) { acc[c] += v[k] * v[l]; ++c; }
        }
        __half2 h0 = __floats2half2_rn(a.x, a.y);
        __half2 h1 = __floats2half2_rn(bq.x, bq.y);
        __half2 h2 = __floats2half2_rn(cq.x, cq.y);
        const int b = (ij.x << 2) | (ij.y >> 7);
        const int rank = atomicAdd(&lcur[b], 1);  // LDS returning int atomic (cheap)
        uint4 r;
        r.x = *(const unsigned int*)&h0;
        r.y = *(const unsigned int*)&h1;
        r.z = *(const unsigned int*)&h2;
        r.w = (unsigned int)(ij.y & 127);
        sorted4[lbase[b] + rank] = r;
    }

    const int lane = threadIdx.x & 63, wv = threadIdx.x >> 6;
#pragma unroll
    for (int i = 0; i < 27; ++i) {
        const float s = wave_sum64(acc[i]);
        if (lane == 0) lstats[wv][i] = s;
    }
    __syncthreads();
    if (threadIdx.x < 27) {
        float s = 0.f;
        for (int w = 0; w < 16; ++w) s += lstats[w][threadIdx.x];
        bstats[blk * 32 + threadIdx.x] = s;
    }
}

// ---- K3b: reduce stats, fold BN into linear, pack half2 weights ----
__global__ __launch_bounds__(64) void bnfold_kernel(const float* __restrict__ bstats,
                                                    const float* __restrict__ W,
                                                    const float* __restrict__ b,
                                                    const float* __restrict__ gamma,
                                                    const float* __restrict__ beta,
                                                    float* __restrict__ ws) {
    __shared__ float s27[27];
    __shared__ float m[6], C[36];
    const int t = threadIdx.x;
    if (t < 27) {
        float s = 0.f;
        for (int blk = 0; blk < NBLK; ++blk) s += bstats[blk * 32 + t];
        s27[t] = s;
    }
    __syncthreads();
    if (t == 0) {
        const float invN = 1.0f / (float)NPTS;
        float mm[6];
        for (int k = 0; k < 6; ++k) { mm[k] = s27[k] * invN; m[k] = mm[k]; }
        int c = 6;
        for (int k = 0; k < 6; ++k)
            for (int l = k; l < 6; ++l) {
                const float cov = s27[c] * invN - mm[k] * mm[l];
                ++c;
                C[k * 6 + l] = cov;
                C[l * 6 + k] = cov;
            }
    }
    __syncthreads();
    float w[6];
#pragma unroll
    for (int k = 0; k < 6; ++k) w[k] = W[t * 6 + k];
    float mh = b[t];
#pragma unroll
    for (int k = 0; k < 6; ++k) mh += w[k] * m[k];
    float var = 0.f;
#pragma unroll
    for (int k = 0; k < 6; ++k)
#pragma unroll
        for (int l = 0; l < 6; ++l) var += w[k] * w[l] * C[k * 6 + l];
    const float s = gamma[t] * rsqrtf(var + EPS);
    float wp[6];
#pragma unroll
    for (int k = 0; k < 6; ++k) wp[k] = w[k] * s;
    unsigned int* wsu = (unsigned int*)ws;
    __half2 p0 = __floats2half2_rn(wp[0], wp[1]);
    __half2 p1 = __floats2half2_rn(wp[2], wp[3]);
    __half2 p2 = __floats2half2_rn(wp[4], wp[5]);
    wsu[WS_WPH + t * 3 + 0] = *(const unsigned int*)&p0;
    wsu[WS_WPH + t * 3 + 1] = *(const unsigned int*)&p1;
    wsu[WS_WPH + t * 3 + 2] = *(const unsigned int*)&p2;
    ws[WS_BP + t] = beta[t] + s * (b[t] - mh);
}

// ---- K4: one block per bucket. Cell-sort bucket's records in LDS (int atomics
//      for ranks, wave-0 scan, ds_write scatter), then per-cell register
//      accumulation with broadcast ds_read_b128 and one coalesced store/cell. ----
constexpr int CAP = 1536;  // max staged records per bucket (mean 977, sd 31 -> 18 sigma)

__global__ __launch_bounds__(1024) void accum_kernel(const uint4* __restrict__ sorted4,
                                                     const int* __restrict__ starts,
                                                     const float* __restrict__ wsf,
                                                     float* __restrict__ grid) {
    __shared__ uint4 recs[CAP];        // 24 KB, cell-sorted records
    __shared__ int lhist[CPB];
    __shared__ int cstart[CPB + 1];
    const int t = threadIdx.x, lane = t & 63, wv = t >> 6;

    const int s = starts[blockIdx.x];
    const int e = starts[blockIdx.x + 1];
    const int n = min(e - s, CAP);

    for (int i = t; i < CPB; i += 1024) lhist[i] = 0;

    const unsigned int* wsu = (const unsigned int*)wsf;
    const unsigned int wp0 = wsu[WS_WPH + lane * 3 + 0];
    const unsigned int wp1 = wsu[WS_WPH + lane * 3 + 1];
    const unsigned int wp2 = wsu[WS_WPH + lane * 3 + 2];
    const float bb = wsf[WS_BP + lane];
    __syncthreads();

    // Phase 1: coalesced load (1-2 records/thread) + rank via LDS int atomic
    uint4 r0, r1;
    int rk0 = -1, rk1 = -1, b0 = 0, b1 = 0;
    if (t < n) {
        r0 = sorted4[s + t];
        b0 = (int)r0.w;
        rk0 = atomicAdd(&lhist[b0], 1);
    }
    if (t + 1024 < n) {
        r1 = sorted4[s + t + 1024];
        b1 = (int)r1.w;
        rk1 = atomicAdd(&lhist[b1], 1);
    }
    __syncthreads();

    // Phase 2a: exclusive scan of 128 bins (wave 0, 2 bins/lane)
    if (wv == 0) {
        const int v0 = lhist[2 * lane], v1 = lhist[2 * lane + 1];
        const int v = v0 + v1;
        int incl = v;
#pragma unroll
        for (int d = 1; d < 64; d <<= 1) {
            int u = __shfl_up(incl, d, 64);
            if (lane >= d) incl += u;
        }
        const int excl = incl - v;
        cstart[2 * lane] = excl;
        cstart[2 * lane + 1] = excl + v0;
        if (lane == 63) cstart[CPB] = incl;  // == n
    }
    __syncthreads();

    // Phase 2b: scatter records into cell-sorted LDS slots
    if (rk0 >= 0) recs[cstart[b0] + rk0] = r0;
    if (rk1 >= 0) recs[cstart[b1] + rk1] = r1;
    __syncthreads();

    // Phase 3: per-cell register accumulation; lane = feature; 8 cells/wave
    float* gbase = grid + (size_t)blockIdx.x * (CPB * 64);
    for (int c = wv; c < CPB; c += 16) {
        const int cs = __builtin_amdgcn_readfirstlane(cstart[c]);
        const int ce = __builtin_amdgcn_readfirstlane(cstart[c + 1]);
        float acc = 0.f;
        for (int p = cs; p < ce; ++p) {
            const uint4 r = recs[p];  // broadcast ds_read_b128 (uniform addr)
            const float h = dot2u(r.x, wp0, dot2u(r.y, wp1, dot2u(r.z, wp2, bb)));
            acc += fmaxf(h, 0.f);
        }
        gbase[c * 64 + lane] = acc;   // 256 B coalesced store
    }

    // Overflow fallback (statistically never): records beyond CAP via global atomics,
    // strictly after this block's stores.
    if (e - s > CAP) {
        __syncthreads();
        for (int base = s + CAP + wv * 64; base < e; base += 16 * 64) {
            const int m = min(64, e - base);
            uint4 rec = make_uint4(0u, 0u, 0u, 0u);
            if (lane < m) rec = sorted4[base + lane];
            for (int pt = 0; pt < m; ++pt) {
                const unsigned int c  = __builtin_amdgcn_readlane(rec.w, pt);
                const unsigned int x0 = __builtin_amdgcn_readlane(rec.x, pt);
                const unsigned int x1 = __builtin_amdgcn_readlane(rec.y, pt);
                const unsigned int x2 = __builtin_amdgcn_readlane(rec.z, pt);
                const float h = dot2u(x0, wp0, dot2u(x1, wp1, dot2u(x2, wp2, bb)));
                unsafeAtomicAdd(&gbase[c * 64 + lane], fmaxf(h, 0.f));
            }
        }
    }
}

extern "C" void kernel_launch(void* const* d_in, const int* in_sizes, int n_in,
                              void* d_out, int out_size, void* d_ws, size_t ws_size,
                              hipStream_t stream) {
    const float* x       = (const float*)d_in[0];
    const int2*  indices = (const int2*)d_in[1];
    const float* W       = (const float*)d_in[2];
    const float* b       = (const float*)d_in[3];
    const float* gamma   = (const float*)d_in[4];
    const float* beta    = (const float*)d_in[5];
    float* out = (float*)d_out;
    float* wsf = (float*)d_ws;
    int*   wsi = (int*)d_ws;

    int*   hist    = wsi + WS_HIST;
    int*   bases   = wsi + WS_BASES;
    int*   starts  = wsi + WS_STARTS;
    uint4* sorted4 = (uint4*)(wsi + WS_SORTED);
    float* bstats  = wsf + WS_BSTATS;

    hist_kernel<<<NBLK, 1024, 0, stream>>>(indices, hist);
    colscan_kernel<<<NBUCK / 64, 64, 0, stream>>>(hist, bases, starts);
    scan_kernel<<<1, 1024, 0, stream>>>(starts);
    scatter_kernel<<<NBLK, 1024, 0, stream>>>(x, indices, starts, bases, sorted4, bstats);
    bnfold_kernel<<<1, 64, 0, stream>>>(bstats, W, b, gamma, beta, wsf);
    accum_kernel<<<NBUCK, 1024, 0, stream>>>(sorted4, starts, wsf, out);
}